// Round 1
// 617.661 us; speedup vs baseline: 1.3546x; 1.3546x over previous
//
#include <hip/hip_runtime.h>
#include <hip/hip_bf16.h>

typedef __hip_bfloat16 bf16;
typedef __attribute__((ext_vector_type(8))) short short8;
typedef __attribute__((ext_vector_type(4))) float f32x4;

#define NN   16
#define CIN  512
#define HH   56
#define WW   56
#define BB   (NN*WW)     /* 896 */
#define OO   1024
#define GG   8
#define RL   111         /* 2K-1 */
#define EPSV 1e-5f

// ---- shared LDS layout for kAttn2 (ushort offsets) ----
#define A2_QT  0         /* qT  [64 rows h][40u] cols c0..31          */
#define A2_KT  2560      /* kT  [64][40u]   (inputs end 5120)         */
#define A2_UL  0         /* Ul [56 i][112u d]  overlay after phase 2  */
#define A2_VL  6272      /* Vl [56][112u]      (end 12544)            */
#define A2_P   0         /* P  [64 i][72u j]   overlay after phase 4  */
#define A2_SP  4608      /* S' [64 i][136u d]  (end 13312)            */
#define A2_SIM 13312     /* sim f16 [56][60]   (end 16672)            */
#define A2_VH  13312     /* v half [32 c][72u j] phase 7 (SIM dead)   */
#define A2_TOT 16672     /* 33344 B -> 4 blocks/CU                    */

// relpad (ws) ushort offsets
#define RP_RQ 0          /* [112][40]  4480u */
#define RP_RK 4480       /* [112][40]  4480u */
#define RP_RV 8960       /* [64][136]  8704u  (end 17664) */

static __device__ __forceinline__ float u2f(unsigned short u){
  union { unsigned int i; float f; } x; x.i = ((unsigned int)u) << 16; return x.f;
}
static __device__ __forceinline__ unsigned short f2u(float f){
  union { float f; unsigned int i; } x; x.f = f;
  unsigned int i = x.i;
  unsigned int r = i + 0x7FFFu + ((i >> 16) & 1u);   // RNE
  return (unsigned short)(r >> 16);
}
static __device__ __forceinline__ float ldin(const void* p, size_t i, bool f32){
  return f32 ? ((const float*)p)[i] : u2f(((const unsigned short*)p)[i]);
}

// async global->LDS, 16B per lane (LDS dest must be wave-uniform base + lane*16)
typedef __attribute__((address_space(3))) unsigned int lds_u32;
typedef __attribute__((address_space(1))) const unsigned int glb_u32;
static __device__ __forceinline__ void gl16(const unsigned short* g, unsigned short* l){
  __builtin_amdgcn_global_load_lds((glb_u32*)g, (lds_u32*)l, 16, 0, 0);
}

// ---------------- dtype probe + partial-stat zeroing ----------------
__global__ void kDetect(const void* __restrict__ x, float* __restrict__ part, int* __restrict__ flag){
  const int t = threadIdx.x;     // 128 threads
  for (int i = t; i < 3072; i += 128) part[i] = 0.f;   // psum[64][24] + psq[64][24]
  unsigned short u = ((const unsigned short*)x)[t];
  int e = (u >> 7) & 0xFF;
  int bad = (e < 100 || e > 140) ? 1 : 0;
  __shared__ int cnt;
  if (t == 0) cnt = 0;
  __syncthreads();
  if (bad) atomicAdd(&cnt, 1);
  __syncthreads();
  if (t == 0) *flag = (cnt > 16) ? 1 : 0;   // 1 => inputs are fp32
}

// ---------------- build padded/transposed rel images in ws (once) ----------------
__global__ __launch_bounds__(256) void kPrep(const void* __restrict__ rel, unsigned short* __restrict__ relpad,
                                             const int* __restrict__ dflag){
  const bool f32 = (*dflag != 0);
  const int t = threadIdx.x;
  for (int i = t; i < 8960; i += 256){          // RqT / RkT  [d][c]
    int reg = i / 4480, r = i - reg*4480;
    int d = r / 40, c = r - d*40;
    float v = (d < RL && c < 32) ? ldin(rel, (size_t)(reg*32 + c)*RL + d, f32) : 0.f;
    relpad[i] = f2u(v);
  }
  for (int i = t; i < 8704; i += 256){          // Rv [c][d]
    int c = i / 136, d = i - c*136;
    float v = (d < RL) ? ldin(rel, (size_t)(64 + c)*RL + d, f32) : 0.f;
    relpad[RP_RV + i] = f2u(v);
  }
}

// ---------------- pre-convert w_qkv to bf16 (once) ----------------
__global__ __launch_bounds__(256) void kWPrep(const void* __restrict__ w, unsigned short* __restrict__ wbf,
                                              const int* __restrict__ dflag){
  const bool f32 = (*dflag != 0);
  const size_t i = (size_t)blockIdx.x*256 + threadIdx.x;   // 2048*256 = 524288 = 1024*512
  wbf[i] = f2u(ldin(w, i, f32));
}

// ---------------- transpose x (N,C,H,W) -> xtk[b=(n*W+w)][h][c] ----------------
__global__ __launch_bounds__(256) void kTrans(const void* __restrict__ x, bf16* __restrict__ xtk,
                                              const int* __restrict__ dflag){
  const bool f32 = (*dflag != 0);
  const int h  = blockIdx.x;       // 56
  const int cg = blockIdx.y;       // 4 groups of 128 channels
  const int n  = blockIdx.z;       // 16
  __shared__ unsigned short tile[128][58];
  const size_t rbase = (((size_t)n*CIN + cg*128)*HH + h)*WW;
  for (int idx = threadIdx.x; idx < 128*WW; idx += 256){
    int ci = idx / WW, w = idx - ci*WW;
    tile[ci][w] = f2u(ldin(x, rbase + (size_t)ci*HH*WW + w, f32));
  }
  __syncthreads();
  unsigned short* dst = (unsigned short*)xtk;
  for (int idx = threadIdx.x; idx < WW*128; idx += 256){
    int w = idx >> 7, ci = idx & 127;
    dst[((size_t)(n*WW + w)*HH + h)*CIN + cg*128 + ci] = tile[ci][w];
  }
}

// ---------------- MFMA GEMM: qkv[b][o][h] = sum_c w[o][c] * xtk[b][h][c] ----------------
// 2-phase double-buffered global_load_lds pipeline, bf16 weights pre-converted.
__global__ __launch_bounds__(256) void kGemmQKV(const unsigned short* __restrict__ wbf, const bf16* __restrict__ xtk,
                                                bf16* __restrict__ qkv){
  const int o0 = blockIdx.x * 128;
  const int b0 = blockIdx.y * 2;
  const int t  = threadIdx.x;
  const int lane = t & 63, wv = t >> 6;
  const int q16 = lane >> 4, l16 = lane & 15;

  __shared__ __align__(16) unsigned short Bs[2][3584];   // 2 x 7168 B

  const int g1 = t, g2 = t + 256;
  const int k81 = g1 / 112, j1 = g1 - k81*112;
  const int k82 = g2 / 112, j2 = g2 - k82*112;
  const int bs1 = (j1 >= 56), bs2 = (j2 >= 56);
  const unsigned short* pB1 = (const unsigned short*)xtk
      + ((size_t)(b0 + bs1)*HH + (j1 - 56*bs1))*CIN + k81*8;
  const unsigned short* pB2 = (const unsigned short*)xtk
      + ((size_t)(b0 + bs2)*HH + (j2 - 56*bs2))*CIN + k82*8;
  const bool has2 = (t < 192);   // wave-uniform (waves 0-2)

  const size_t aofs0 = (size_t)(o0 + wv*32 + l16)*CIN + q16*8;
  const size_t aofs1 = aofs0 + (size_t)16*CIN;

  // prologue: stage k-step 0 into buf0, prefetch A regs
  gl16(pB1, &Bs[0][(size_t)t*8]);
  if (has2) gl16(pB2, &Bs[0][(size_t)(t+256)*8]);
  short8 a0 = *(const short8*)(wbf + aofs0);
  short8 a1 = *(const short8*)(wbf + aofs1);

  f32x4 acc[2][7];
  #pragma unroll
  for (int mt = 0; mt < 2; ++mt)
    #pragma unroll
    for (int nt = 0; nt < 7; ++nt) acc[mt][nt] = (f32x4){0.f,0.f,0.f,0.f};

  __syncthreads();   // drains vmcnt(0) -> buf0 ready

  #pragma unroll
  for (int kk = 0; kk < 16; ++kk){
    const int cur = kk & 1;
    if (kk < 15){                               // issue next-step staging (async)
      const int ko = (kk + 1)*32;
      gl16(pB1 + ko, &Bs[cur^1][(size_t)t*8]);
      if (has2) gl16(pB2 + ko, &Bs[cur^1][(size_t)(t+256)*8]);
    }
    const short8 ca0 = a0, ca1 = a1;
    if (kk < 15){                               // prefetch next A regs (L2-hot)
      const int ko = (kk + 1)*32;
      a0 = *(const short8*)(wbf + aofs0 + ko);
      a1 = *(const short8*)(wbf + aofs1 + ko);
    }
    #pragma unroll
    for (int nt = 0; nt < 7; ++nt){
      const short8 bf = *(const short8*)&Bs[cur][(q16*112 + nt*16 + l16)*8];
      acc[0][nt] = __builtin_amdgcn_mfma_f32_16x16x32_bf16(ca0, bf, acc[0][nt], 0, 0, 0);
      acc[1][nt] = __builtin_amdgcn_mfma_f32_16x16x32_bf16(ca1, bf, acc[1][nt], 0, 0, 0);
    }
    if (kk < 15) __syncthreads();               // one barrier per K-step (drains staging)
  }

  unsigned short* dst = (unsigned short*)qkv;
  #pragma unroll
  for (int nt = 0; nt < 7; ++nt){
    const int j  = nt*16 + l16;
    const int bs = (j >= 56);
    const int h  = j - 56*bs;
    #pragma unroll
    for (int mt = 0; mt < 2; ++mt){
      const int orow = o0 + wv*32 + mt*16 + q16*4;
      size_t base = ((size_t)(b0 + bs)*OO + orow)*HH + h;
      #pragma unroll
      for (int r = 0; r < 4; ++r)
        dst[base + (size_t)r*HH] = f2u(acc[mt][nt][r]);
    }
  }
}

// ---------------- per-channel BN stats over [b][o][h] -> scale/shift ----------------
__global__ __launch_bounds__(256) void kStatO(const bf16* __restrict__ t, const void* __restrict__ gamma,
                                              const void* __restrict__ beta,
                                              float* __restrict__ sc, float* __restrict__ sh,
                                              const int* __restrict__ dflag){
  const bool f32 = (*dflag != 0);
  const int o = blockIdx.x;
  const unsigned short* p = (const unsigned short*)t;
  float s = 0.f, sq = 0.f;
  for (int q = threadIdx.x; q < BB*7; q += 256){
    int b = q / 7, hq = q - b*7;
    short8 u = *(const short8*)(p + ((size_t)b*OO + o)*HH + hq*8);
    #pragma unroll
    for (int e = 0; e < 8; ++e){
      float v = u2f((unsigned short)u[e]);
      s += v; sq += v*v;
    }
  }
  #pragma unroll
  for (int off = 32; off > 0; off >>= 1){ s += __shfl_down(s, off); sq += __shfl_down(sq, off); }
  __shared__ float rs[4], rq[4];
  const int wid = threadIdx.x >> 6;
  if ((threadIdx.x & 63) == 0){ rs[wid] = s; rq[wid] = sq; }
  __syncthreads();
  if (threadIdx.x == 0){
    float S = rs[0]+rs[1]+rs[2]+rs[3], Q = rq[0]+rq[1]+rq[2]+rq[3];
    const float cnt = (float)(BB*HH);
    float mean = S / cnt;
    float var  = Q / cnt - mean*mean;
    float scale = ldin(gamma, o, f32) * rsqrtf(var + EPSV);
    sc[o] = scale; sh[o] = ldin(beta, o, f32) - mean*scale;
  }
}

// ============ shared helpers: q/k staging + score MFMAs (rel read direct from global) ============
static __device__ __forceinline__ void stageQK(unsigned short* sm, const unsigned short* qkv,
                                               const float* __restrict__ sc1, const float* __restrict__ sh1,
                                               int b, int g, int t){
  const unsigned short* qp = qkv + (size_t)(b*OO + g*128)*HH;
  for (int q = t; q < 896; q += 256){           // q/k rows, ushort4
    int c = q / 14, hq = q - c*14;
    int o = g*128 + c;
    ushort4 u = *(const ushort4*)(qp + (size_t)c*HH + hq*4);
    float s = sc1[o], hb = sh1[o];
    int base = (c < 32 ? A2_QT : A2_KT) + (c & 31) + hq*160;
    sm[base]       = f2u(u2f(u.x)*s + hb);
    sm[base + 40]  = f2u(u2f(u.y)*s + hb);
    sm[base + 80]  = f2u(u2f(u.z)*s + hb);
    sm[base + 120] = f2u(u2f(u.w)*s + hb);
  }
  for (int i = t; i < 640; i += 256){           // zero rows 56..63 of qT/kT
    int a = i / 320, r = i - a*320;
    sm[(a ? A2_KT : A2_QT) + 2240 + r] = 0;
  }
}

static __device__ __forceinline__ void scoreMFMA(const unsigned short* sm,
                                                 const unsigned short* __restrict__ relpad,
                                                 int w, int q16, int l16,
                                                 f32x4 aqk[4], f32x4 aU[7], f32x4 aV[7]){
  const short8 aq = *(const short8*)&sm[A2_QT + (w*16 + l16)*40 + q16*8];
  const short8 ak = *(const short8*)&sm[A2_KT + (w*16 + l16)*40 + q16*8];
  #pragma unroll
  for (int nt = 0; nt < 4; ++nt){
    const short8 bk = *(const short8*)&sm[A2_KT + (nt*16 + l16)*40 + q16*8];
    aqk[nt] = __builtin_amdgcn_mfma_f32_16x16x32_bf16(aq, bk, aqk[nt], 0, 0, 0);
  }
  #pragma unroll
  for (int nt = 0; nt < 7; ++nt){
    const short8 bq = *(const short8*)(relpad + RP_RQ + (nt*16 + l16)*40 + q16*8);
    const short8 br = *(const short8*)(relpad + RP_RK + (nt*16 + l16)*40 + q16*8);
    aU[nt] = __builtin_amdgcn_mfma_f32_16x16x32_bf16(aq, bq, aU[nt], 0, 0, 0);
    aV[nt] = __builtin_amdgcn_mfma_f32_16x16x32_bf16(ak, br, aV[nt], 0, 0, 0);
  }
}

static __device__ __forceinline__ void writeUV(unsigned short* sm, int w, int q16, int l16,
                                               const f32x4 aU[7], const f32x4 aV[7]){
  #pragma unroll
  for (int nt = 0; nt < 7; ++nt){
    const int d = nt*16 + l16;
    #pragma unroll
    for (int r = 0; r < 4; ++r){
      const int i = w*16 + q16*4 + r;
      if (i < HH){
        sm[A2_UL + i*112 + d] = f2u(aU[nt][r]);
        sm[A2_VL + i*112 + d] = f2u(aV[nt][r]);
      }
    }
  }
}

// ---------------- kScore: MFMA scores -> BN2 stats, all in registers ----------------
// qr[i,j]=U[i,i-j+55] covers exactly the band d in [row,row+55]: a per-lane
// predicate on the accumulators -> no LDS round trip, no gather, no conflicts.
__global__ __launch_bounds__(256) void kScore(const bf16* __restrict__ qkv,
                                              const unsigned short* __restrict__ relpad,
                                              const float* __restrict__ sc1, const float* __restrict__ sh1,
                                              float* __restrict__ psum, float* __restrict__ psq){
  const int b = blockIdx.x, g = blockIdx.y;
  __shared__ __align__(16) unsigned short sm[5120];   // qT/kT only (10 KB)
  __shared__ float red[6][4];
  const int t = threadIdx.x;
  const int lane = t & 63, w = t >> 6;
  const int q16 = lane >> 4, l16 = lane & 15;

  stageQK(sm, (const unsigned short*)qkv, sc1, sh1, b, g, t);
  __syncthreads();

  f32x4 aqk[4], aU[7], aV[7];
  #pragma unroll
  for (int nt = 0; nt < 4; ++nt) aqk[nt] = (f32x4){0.f,0.f,0.f,0.f};
  #pragma unroll
  for (int nt = 0; nt < 7; ++nt){ aU[nt] = (f32x4){0.f,0.f,0.f,0.f}; aV[nt] = (f32x4){0.f,0.f,0.f,0.f}; }
  scoreMFMA(sm, relpad, w, q16, l16, aqk, aU, aV);

  float s0=0.f,s1=0.f,s2=0.f,p0=0.f,p1=0.f,p2=0.f;
  #pragma unroll
  for (int nt = 0; nt < 4; ++nt){
    const int j = nt*16 + l16;
    #pragma unroll
    for (int r = 0; r < 4; ++r){
      const int i = w*16 + q16*4 + r;
      if (i < HH && j < HH){ float v = aqk[nt][r]; s0 += v; p0 += v*v; }
    }
  }
  #pragma unroll
  for (int nt = 0; nt < 7; ++nt){
    const int d = nt*16 + l16;
    #pragma unroll
    for (int r = 0; r < 4; ++r){
      const int row = w*16 + q16*4 + r;
      if (row < HH && (unsigned)(d - row) < (unsigned)HH){
        float u = aU[nt][r]; s1 += u; p1 += u*u;
        float v = aV[nt][r]; s2 += v; p2 += v*v;
      }
    }
  }
  float s[3] = {s0,s1,s2}, q2[3] = {p0,p1,p2};
  #pragma unroll
  for (int off = 32; off > 0; off >>= 1)
    #pragma unroll
    for (int m = 0; m < 3; ++m){ s[m]+=__shfl_down(s[m],off); q2[m]+=__shfl_down(q2[m],off); }
  if ((t & 63) == 0){
    #pragma unroll
    for (int m = 0; m < 3; ++m){ red[m][w] = s[m]; red[3+m][w] = q2[m]; }
  }
  __syncthreads();
  if (t < 6){
    float v = red[t][0]+red[t][1]+red[t][2]+red[t][3];
    int m = t % 3;
    int ch = m*8 + g;
    float* dstp = (t >= 3) ? psq : psum;
    atomicAdd(&dstp[(b & 63)*24 + ch], v);    // 64-slot spread: no same-line pileup
  }
}

__global__ void kF2(const float* __restrict__ psum, const float* __restrict__ psq,
                    const void* __restrict__ gs, const void* __restrict__ bs,
                    float* __restrict__ sc2, float* __restrict__ sh2,
                    const int* __restrict__ dflag){
  const bool f32 = (*dflag != 0);
  const int ch = threadIdx.x;
  if (ch < 24){
    float S = 0.f, Q = 0.f;
    for (int sl = 0; sl < 64; ++sl){ S += psum[sl*24 + ch]; Q += psq[sl*24 + ch]; }
    const float cnt = (float)BB * (float)(HH*HH);
    float mean = S / cnt;
    float var  = Q / cnt - mean*mean;
    float scale = ldin(gs, ch, f32) * rsqrtf(var + EPSV);
    sc2[ch] = scale; sh2[ch] = ldin(bs, ch, f32) - mean*scale;
  }
}

// ---------------- kAttn2: scores -> BN2 -> softmax -> PV ----------------
__global__ __launch_bounds__(256) void kAttn2(const bf16* __restrict__ qkv,
                                              const unsigned short* __restrict__ relpad,
                                              const float* __restrict__ sc1, const float* __restrict__ sh1,
                                              const float* __restrict__ sc2, const float* __restrict__ sh2,
                                              bf16* __restrict__ outr){
  const int b = blockIdx.x, g = blockIdx.y;
  __shared__ __align__(16) unsigned short sm[A2_TOT];
  const int t = threadIdx.x;
  const int lane = t & 63, w = t >> 6;
  const int q16 = lane >> 4, l16 = lane & 15;

  // phase 1: q/k staging only (rel stays in global/L1)
  stageQK(sm, (const unsigned short*)qkv, sc1, sh1, b, g, t);
  __syncthreads();

  // phase 2: score MFMAs
  f32x4 aqk[4], aU[7], aV[7];
  #pragma unroll
  for (int nt = 0; nt < 4; ++nt) aqk[nt] = (f32x4){0.f,0.f,0.f,0.f};
  #pragma unroll
  for (int nt = 0; nt < 7; ++nt){ aU[nt] = (f32x4){0.f,0.f,0.f,0.f}; aV[nt] = (f32x4){0.f,0.f,0.f,0.f}; }
  scoreMFMA(sm, relpad, w, q16, l16, aqk, aU, aV);
  __syncthreads();

  // phase 3: Ul/Vl overlay
  writeUV(sm, w, q16, l16, aU, aV);
  __syncthreads();

  // phase 4: sim = BN2(qk)+BN2(qr)+BN2(kr), f16
  {
    const float scqk=sc2[g],    shqk=sh2[g];
    const float scqr=sc2[8+g],  shqr=sh2[8+g];
    const float sckr=sc2[16+g], shkr=sh2[16+g];
    _Float16* simh = (_Float16*)&sm[A2_SIM];
    #pragma unroll
    for (int nt = 0; nt < 4; ++nt){
      const int j = nt*16 + l16;
      #pragma unroll
      for (int r = 0; r < 4; ++r){
        const int i = w*16 + q16*4 + r;
        if (i < HH && j < HH){
          float qr = u2f(sm[A2_UL + i*112 + (i - j + 55)]);
          float kr = u2f(sm[A2_VL + j*112 + (j - i + 55)]);
          float sv_ = aqk[nt][r]*scqk + shqk + qr*scqr + shqr + kr*sckr + shkr;
          simh[i*60 + j] = (_Float16)sv_;
        }
      }
    }
  }
  __syncthreads();

  // phase 5: zero P/S' (13312u = 6656 dwords)
  for (int i = t; i < 6656; i += 256) ((unsigned int*)sm)[i] = 0u;
  __syncthreads();

  // phase 6: softmax rows -> P and gathered S'
  if (t < 224){
    const _Float16* simh = (const _Float16*)&sm[A2_SIM];
    const int r = t >> 2, l4 = t & 3;
    float pvv[14]; float mx = -1e30f;
    #pragma unroll
    for (int m = 0; m < 14; ++m){ pvv[m] = (float)simh[r*60 + l4 + 4*m]; mx = fmaxf(mx, pvv[m]); }
    mx = fmaxf(mx, __shfl_xor(mx, 1)); mx = fmaxf(mx, __shfl_xor(mx, 2));
    float smm = 0.f;
    #pragma unroll
    for (int m = 0; m < 14; ++m){ pvv[m] = __expf(pvv[m] - mx); smm += pvv[m]; }
    smm += __shfl_xor(smm, 1); smm += __shfl_xor(smm, 2);
    const float inv = 1.f / smm;
    #pragma unroll
    for (int m = 0; m < 14; ++m){
      const int j = l4 + 4*m;
      unsigned short pu = f2u(pvv[m]*inv);
      sm[A2_P  + r*72  + j]            = pu;
      sm[A2_SP + r*136 + (r - j + 55)] = pu;
    }
  }
  __syncthreads();

  // phase 7: PV in two c-halves (v staged into dead sim region; Rv read direct)
  f32x4 asv[4], asve[4];
  #pragma unroll
  for (int nt = 0; nt < 4; ++nt){ asv[nt] = (f32x4){0.f,0.f,0.f,0.f}; asve[nt] = (f32x4){0.f,0.f,0.f,0.f}; }
  const short8 ap0 = *(const short8*)&sm[A2_P + (w*16 + l16)*72 + q16*8];
  const short8 ap1 = *(const short8*)&sm[A2_P + (w*16 + l16)*72 + 32 + q16*8];
  short8 asp[4];
  #pragma unroll
  for (int kk = 0; kk < 4; ++kk)
    asp[kk] = *(const short8*)&sm[A2_SP + (w*16 + l16)*136 + kk*32 + q16*8];

  #pragma unroll
  for (int half = 0; half < 2; ++half){
    // stage v half: 32 rows x 56 j (+ zero cols 56..63)
    const unsigned short* vp = (const unsigned short*)qkv
        + ((size_t)b*OO + g*128 + 64 + half*32)*HH;
    for (int q = t; q < 448; q += 256){
      int c2 = q / 14, hq = q - c2*14;
      int o = g*128 + 64 + half*32 + c2;
      ushort4 u = *(const ushort4*)(vp + (size_t)c2*HH + hq*4);
      float s = sc1[o], hb = sh1[o];
      unsigned short* d = &sm[A2_VH + c2*72 + hq*4];
      d[0] = f2u(u2f(u.x)*s + hb);
      d[1] = f2u(u2f(u.y)*s + hb);
      d[2] = f2u(u2f(u.z)*s + hb);
      d[3] = f2u(u2f(u.w)*s + hb);
    }
    if (t < 256){ int c2 = t >> 3, e = t & 7; sm[A2_VH + c2*72 + 56 + e] = 0; }
    __syncthreads();
    #pragma unroll
    for (int ntl = 0; ntl < 2; ++ntl){
      const int nt = half*2 + ntl;
      const short8 bv0 = *(const short8*)&sm[A2_VH + (ntl*16 + l16)*72 + q16*8];
      const short8 bv1 = *(const short8*)&sm[A2_VH + (ntl*16 + l16)*72 + 32 + q16*8];
      asv[nt] = __builtin_amdgcn_mfma_f32_16x16x32_bf16(ap0, bv0, asv[nt], 0, 0, 0);
      asv[nt] = __builtin_amdgcn_mfma_f32_16x16x32_bf16(ap1, bv1, asv[nt], 0, 0, 0);
      #pragma unroll
      for (int kk = 0; kk < 4; ++kk){
        const short8 br = *(const short8*)(relpad + RP_RV
            + (size_t)(half*32 + ntl*16 + l16)*136 + kk*32 + q16*8);
        asve[nt] = __builtin_amdgcn_mfma_f32_16x16x32_bf16(asp[kk], br, asve[nt], 0, 0, 0);
      }
    }
    __syncthreads();
  }

  // epilogue
  const int i0 = w*16 + q16*4;
  if (i0 < HH){
    unsigned short* op = (unsigned short*)outr + (size_t)b*OO*HH;
    #pragma unroll
    for (int nt = 0; nt < 4; ++nt){
      const int c = nt*16 + l16;
      const int och = (g*64 + c)*2;
      *(ushort4*)(op + (size_t)och*HH + i0) =
        make_ushort4(f2u(asv[nt][0]),  f2u(asv[nt][1]),  f2u(asv[nt][2]),  f2u(asv[nt][3]));
      *(ushort4*)(op + (size_t)(och+1)*HH + i0) =
        make_ushort4(f2u(asve[nt][0]), f2u(asve[nt][1]), f2u(asve[nt][2]), f2u(asve[nt][3]));
    }
  }
}

// ---------------- BN3 + pair-sum + transpose to (N,512,H,W) ----------------
__global__ __launch_bounds__(256) void kOut(const bf16* __restrict__ outr, const float* __restrict__ sc3,
                                            const float* __restrict__ sh3, void* __restrict__ out,
                                            const int* __restrict__ dflag){
  const bool f32 = (*dflag != 0);
  const int p = blockIdx.x, n = blockIdx.y;
  __shared__ float tile[HH][WW+1];
  const unsigned short* ip = (const unsigned short*)outr;
  const float s0 = sc3[2*p], h0 = sh3[2*p], s1 = sc3[2*p+1], h1 = sh3[2*p+1];
  for (int idx = threadIdx.x; idx < HH*WW; idx += 256){
    int w = idx / HH, h = idx - w*HH;
    size_t base = ((size_t)((n*WW + w)*OO) + 2*p)*HH + h;
    float a = u2f(ip[base]);
    float c = u2f(ip[base + HH]);
    tile[h][w] = a*s0 + h0 + c*s1 + h1;
  }
  __syncthreads();
  const size_t obase = ((size_t)(n*512 + p))*HH*WW;
  for (int idx = threadIdx.x; idx < HH*WW; idx += 256){
    int h = idx / WW, w = idx - h*WW;
    float v = tile[h][w];
    if (f32) ((float*)out)[obase + idx] = v;
    else     ((unsigned short*)out)[obase + idx] = f2u(v);
  }
}

extern "C" void kernel_launch(void* const* d_in, const int* in_sizes, int n_in,
                              void* d_out, int out_size, void* d_ws, size_t ws_size,
                              hipStream_t stream){
  (void)in_sizes; (void)n_in; (void)out_size; (void)ws_size;
  const void* x    = d_in[0];
  const void* wqkv = d_in[1];
  const void* rel  = d_in[2];
  const void* gq   = d_in[3];
  const void* bq   = d_in[4];
  const void* gs   = d_in[5];
  const void* bs   = d_in[6];
  const void* go   = d_in[7];
  const void* bo   = d_in[8];

  char* ws = (char*)d_ws;
  const size_t szA = (size_t)BB*OO*HH*2;   // 102,760,448 B
  bf16* xtk  = (bf16*)ws;                  // [B][H][C] = 51.4 MB (dead after GEMM)
  bf16* outr = (bf16*)ws;                  // [B][O][H] (reuses region A)
  // bf16 weights live in region A after xtk (51.4 MB) and before outr exists
  unsigned short* wbf = (unsigned short*)(ws + (size_t)64*1024*1024);   // 1 MB
  bf16* qkv  = (bf16*)(ws + szA);          // [B][O][H]
  float* st  = (float*)(ws + 2*szA);
  float* sc1   = st;
  float* sh1   = st + 1024;
  float* sc3   = st + 2048;
  float* sh3   = st + 3072;
  float* sc2   = st + 4096;
  float* sh2   = st + 4128;
  int*   flag  = (int*)(st + 4160);
  float* psum  = st + 4352;                // [64][24]
  float* psq   = st + 5888;                // [64][24] (ends 7424 < 8192)
  unsigned short* relpad = (unsigned short*)(ws + 2*szA + 32768);  // 17664u

  kDetect <<<1, 128, 0, stream>>>(x, psum, flag);
  kPrep   <<<1, 256, 0, stream>>>(rel, relpad, flag);
  kWPrep  <<<2048, 256, 0, stream>>>(wqkv, wbf, flag);
  kTrans  <<<dim3(HH, 4, NN), 256, 0, stream>>>(x, xtk, flag);
  kGemmQKV<<<dim3(8, BB/2), 256, 0, stream>>>(wbf, xtk, qkv);
  kStatO  <<<OO, 256, 0, stream>>>(qkv, gq, bq, sc1, sh1, flag);
  kScore  <<<dim3(BB, GG), 256, 0, stream>>>(qkv, relpad, sc1, sh1, psum, psq);
  kF2     <<<1, 64, 0, stream>>>(psum, psq, gs, bs, sc2, sh2, flag);
  kAttn2  <<<dim3(BB, GG), 256, 0, stream>>>(qkv, relpad, sc1, sh1, sc2, sh2, outr);
  kStatO  <<<OO, 256, 0, stream>>>(outr, go, bo, sc3, sh3, flag);
  kOut    <<<dim3(512, NN), 256, 0, stream>>>(outr, sc3, sh3, d_out, flag);
}